// Round 4
// baseline (295.206 us; speedup 1.0000x reference)
//
#include <hip/hip_runtime.h>
#include <hip/hip_bf16.h>

#define HW 16384
#define DIM 192
#define DIM2 384
#define NB 8
#define HEADS 8
#define CD 24
#define NSPLIT 64

typedef float f32x4 __attribute__((ext_vector_type(4)));
typedef short bf16x8 __attribute__((ext_vector_type(8)));

__device__ __forceinline__ short f2bf(float f) {
    __hip_bfloat16 h = __float2bfloat16(f);
    return *reinterpret_cast<short*>(&h);
}
__device__ __forceinline__ float bf2f(short s) {
    __hip_bfloat16 h = *reinterpret_cast<__hip_bfloat16*>(&s);
    return __bfloat162float(h);
}

// ---------------------------------------------------------------------------
// prep: w1 (384x192 f32) -> bf16
// ---------------------------------------------------------------------------
__global__ __launch_bounds__(256)
void prep_w1(const float* __restrict__ w1, short* __restrict__ wb1)
{
    int i = (blockIdx.x * 256 + threadIdx.x) * 4;
    float4 v = *reinterpret_cast<const float4*>(w1 + i);
    *reinterpret_cast<short4*>(wb1 + i) =
        make_short4(f2bf(v.x), f2bf(v.y), f2bf(v.z), f2bf(v.w));
}

// ---------------------------------------------------------------------------
// MFMA GEMM, K=192: C[b][oc][px] = sum_ic A[oc][ic] * B[b][ic][px].
// Block = 128-px slab x all OC. B staged through chunked double-buffered LDS
// ([128px][32k] tiles, stride 40 shorts, 8-granule XOR swizzle) then ALL 12
// B-fragments hoisted to registers. Main loop: A global b128 loads (ping-pong
// prefetch) + MFMA only — no LDS, no barriers.
// ---------------------------------------------------------------------------
template<int NOCT, bool B_F32, bool PER_BATCH_A, bool OUT_F32>
__global__ __launch_bounds__(256, 3)
void gemm_k192(const short* __restrict__ Ab, const void* __restrict__ Bg,
               void* __restrict__ Cg, long bstrideB, long bstrideC)
{
    __shared__ short ldsch[2][128 * 40];
    const int tid  = threadIdx.x;
    const int lane = tid & 63;
    const int wave = tid >> 6;
    const int px0  = blockIdx.x * 128;
    const int b    = blockIdx.y;

    const int row  = lane & 15;
    const int kgrp = lane >> 4;          // 0..3
    const short* A0 = Ab + (PER_BATCH_A ? (long)b * NOCT * 16 * DIM : 0);

    bf16x8 aA[6], aB[6];
    auto loadA = [&](bf16x8* dst, int mi) {
#pragma unroll
        for (int c = 0; c < 6; c++)
            dst[c] = *reinterpret_cast<const bf16x8*>(
                &A0[(long)(mi * 16 + row) * DIM + c * 32 + kgrp * 8]);
    };
    loadA(aA, 0);   // issue before staging: overlaps with B traffic

    // ---- stage one 32-k chunk of B, transposed + granule-swizzled ----
    const int q  = tid & 31;             // px quad 0..31
    const int kq = tid >> 5;             // 0..7 (4 k each)
    auto stage = [&](int c, int buf) {
        const int kk = c * 32 + kq * 4;
        short4 t0, t1, t2, t3;
        if constexpr (B_F32) {
            const float* src = (const float*)Bg + (long)b * bstrideB + (long)kk * HW + px0 + q * 4;
            float4 v0 = *(const float4*)(src);
            float4 v1 = *(const float4*)(src + HW);
            float4 v2 = *(const float4*)(src + 2L * HW);
            float4 v3 = *(const float4*)(src + 3L * HW);
            t0 = make_short4(f2bf(v0.x), f2bf(v1.x), f2bf(v2.x), f2bf(v3.x));
            t1 = make_short4(f2bf(v0.y), f2bf(v1.y), f2bf(v2.y), f2bf(v3.y));
            t2 = make_short4(f2bf(v0.z), f2bf(v1.z), f2bf(v2.z), f2bf(v3.z));
            t3 = make_short4(f2bf(v0.w), f2bf(v1.w), f2bf(v2.w), f2bf(v3.w));
        } else {
            const short* src = (const short*)Bg + (long)b * bstrideB + (long)kk * HW + px0 + q * 4;
            short4 v0 = *(const short4*)(src);
            short4 v1 = *(const short4*)(src + HW);
            short4 v2 = *(const short4*)(src + 2L * HW);
            short4 v3 = *(const short4*)(src + 3L * HW);
            t0 = make_short4(v0.x, v1.x, v2.x, v3.x);
            t1 = make_short4(v0.y, v1.y, v2.y, v3.y);
            t2 = make_short4(v0.z, v1.z, v2.z, v3.z);
            t3 = make_short4(v0.w, v1.w, v2.w, v3.w);
        }
        // chunk-local k' = kq*4: granule kq>>1, offset (kq&1)*4; sigma = q&3
        const int goff = (((kq >> 1) ^ (q & 3)) << 3) + (kq & 1) * 4;
        short* dst = &ldsch[buf][0];
        *(short4*)&dst[(q * 4 + 0) * 40 + goff] = t0;
        *(short4*)&dst[(q * 4 + 1) * 40 + goff] = t1;
        *(short4*)&dst[(q * 4 + 2) * 40 + goff] = t2;
        *(short4*)&dst[(q * 4 + 3) * 40 + goff] = t3;
    };

    // ---- hoist all 12 B-fragments to registers (chunk double-buffer) ----
    bf16x8 bv[2][6];
    const int bro = wave * 32 + row;
    const int sgr = (row >> 2) & 3;
    stage(0, 0);
#pragma unroll
    for (int c = 0; c < 6; c++) {
        __syncthreads();
        if (c < 5) stage(c + 1, (c + 1) & 1);
        const short* base = &ldsch[c & 1][0];
        bv[0][c] = *(const bf16x8*)&base[bro * 40 + ((kgrp ^ sgr) << 3)];
        bv[1][c] = *(const bf16x8*)&base[(bro + 16) * 40 + ((kgrp ^ sgr) << 3)];
    }

    // ---- main loop: A-prefetch ping-pong + MFMA, barrier-free ----
    auto computeStore = [&](const bf16x8* a, int mi) {
        f32x4 acc0 = (f32x4){0.f, 0.f, 0.f, 0.f};
        f32x4 acc1 = (f32x4){0.f, 0.f, 0.f, 0.f};
#pragma unroll
        for (int c = 0; c < 6; c++) {
            acc0 = __builtin_amdgcn_mfma_f32_16x16x32_bf16(a[c], bv[0][c], acc0, 0, 0, 0);
            acc1 = __builtin_amdgcn_mfma_f32_16x16x32_bf16(a[c], bv[1][c], acc1, 0, 0, 0);
        }
        const int ocb = mi * 16 + kgrp * 4;
        const int pxb = px0 + wave * 32 + row;
#pragma unroll
        for (int r = 0; r < 4; r++) {
            long off0 = (long)b * bstrideC + (long)(ocb + r) * HW + pxb;
            if constexpr (OUT_F32) {
                ((float*)Cg)[off0]      = acc0[r];
                ((float*)Cg)[off0 + 16] = acc1[r];
            } else {
                ((short*)Cg)[off0]      = f2bf(acc0[r]);
                ((short*)Cg)[off0 + 16] = f2bf(acc1[r]);
            }
        }
    };

    for (int mi = 0; mi < NOCT; mi += 2) {
        loadA(aB, mi + 1);
        computeStore(aA, mi);
        if (mi + 2 < NOCT) loadA(aA, mi + 2);
        computeStore(aB, mi + 1);
    }
}

// ---------------------------------------------------------------------------
// depthwise 3x3 (pad 1), one 128x128 image per block; bf16 in/out,
// fused sum-of-squares for k channels (gc < 192).
// ---------------------------------------------------------------------------
__global__ __launch_bounds__(256)
void dwconv_sumsq(const short* __restrict__ in, const float* __restrict__ w2,
                  short* __restrict__ outp, float* __restrict__ kss)
{
    __shared__ short img[16384];
    __shared__ float red[4];
    const long bgc = blockIdx.x;           // b*384 + gc
    const int  gc  = (int)(bgc % DIM2);
    const int  b   = (int)(bgc / DIM2);
    const int  tid = threadIdx.x;
    const short* src = in + (bgc << 14);
#pragma unroll
    for (int j = 0; j < 16; j++) {
        int idx = (tid + j * 256) * 4;
        *reinterpret_cast<short4*>(&img[idx]) = *reinterpret_cast<const short4*>(&src[idx]);
    }
    float wv[9];
#pragma unroll
    for (int i = 0; i < 9; i++) wv[i] = w2[gc * 9 + i];
    __syncthreads();

    short* dst = outp + (bgc << 14);
    float ssq = 0.f;
    for (int j = 0; j < 64; j++) {
        int px = tid + j * 256;
        int y = px >> 7, x = px & 127;
        float s = 0.f;
#pragma unroll
        for (int dy = 0; dy < 3; dy++) {
            int yy = y + dy - 1;
            if ((unsigned)yy > 127u) continue;
#pragma unroll
            for (int dx = 0; dx < 3; dx++) {
                int xx = x + dx - 1;
                if ((unsigned)xx > 127u) continue;
                s += wv[dy * 3 + dx] * bf2f(img[yy * 128 + xx]);
            }
        }
        dst[px] = f2bf(s);
        ssq += s * s;
    }
    for (int o = 32; o; o >>= 1) ssq += __shfl_xor(ssq, o);
    if ((tid & 63) == 0) red[tid >> 6] = ssq;
    __syncthreads();
    if (gc < DIM && tid == 0)
        kss[b * DIM + gc] = red[0] + red[1] + red[2] + red[3];
}

// ---------------------------------------------------------------------------
// QK^T via MFMA over contiguous px. Zero LDS/transpose. Grid (NSPLIT, 64 bh);
// 1 wave computes 32x32 over HW/NSPLIT px. Fused q sumsq partials.
// ---------------------------------------------------------------------------
__global__ __launch_bounds__(64)
void qk_mfma(const float* __restrict__ q, const short* __restrict__ kvb,
             float* __restrict__ part, float* __restrict__ pssq)
{
    const int split = blockIdx.x;          // 0..NSPLIT-1
    const int bh    = blockIdx.y;          // b*8 + h
    const int b = bh >> 3, h = bh & 7;
    const int lane = threadIdx.x;
    const int row = lane & 15;
    const int kg  = (lane >> 4) * 8;
    const int CHUNK = HW / NSPLIT;         // 256

    const int qr1 = min(h * CD + 16 + row, DIM - 1);   // clamp (h=7 tail OOB)
    const float* q0 = q + ((long)b * DIM + h * CD + row) * HW + split * CHUNK + kg;
    const float* q1 = q + ((long)b * DIM + qr1) * HW + split * CHUNK + kg;
    const short* k0 = kvb + ((long)b * DIM2 + h * CD + row) * HW + split * CHUNK + kg;
    const short* k1 = k0 + 16L * HW;

    f32x4 acc[2][2];
#pragma unroll
    for (int m = 0; m < 2; m++)
#pragma unroll
        for (int n = 0; n < 2; n++) acc[m][n] = (f32x4){0.f, 0.f, 0.f, 0.f};
    float ssq0 = 0.f, ssq1 = 0.f;

#pragma unroll
    for (int s = 0; s < CHUNK / 32; s++) {
        const int px = s * 32;
        float4 qa = *reinterpret_cast<const float4*>(q0 + px);
        float4 qb = *reinterpret_cast<const float4*>(q0 + px + 4);
        float4 qc = *reinterpret_cast<const float4*>(q1 + px);
        float4 qd = *reinterpret_cast<const float4*>(q1 + px + 4);
        bf16x8 b0 = *reinterpret_cast<const bf16x8*>(k0 + px);
        bf16x8 b1 = *reinterpret_cast<const bf16x8*>(k1 + px);
        ssq0 += qa.x*qa.x + qa.y*qa.y + qa.z*qa.z + qa.w*qa.w
              + qb.x*qb.x + qb.y*qb.y + qb.z*qb.z + qb.w*qb.w;
        ssq1 += qc.x*qc.x + qc.y*qc.y + qc.z*qc.z + qc.w*qc.w
              + qd.x*qd.x + qd.y*qd.y + qd.z*qd.z + qd.w*qd.w;
        bf16x8 a0, a1;
        a0[0]=f2bf(qa.x); a0[1]=f2bf(qa.y); a0[2]=f2bf(qa.z); a0[3]=f2bf(qa.w);
        a0[4]=f2bf(qb.x); a0[5]=f2bf(qb.y); a0[6]=f2bf(qb.z); a0[7]=f2bf(qb.w);
        a1[0]=f2bf(qc.x); a1[1]=f2bf(qc.y); a1[2]=f2bf(qc.z); a1[3]=f2bf(qc.w);
        a1[4]=f2bf(qd.x); a1[5]=f2bf(qd.y); a1[6]=f2bf(qd.z); a1[7]=f2bf(qd.w);
        acc[0][0] = __builtin_amdgcn_mfma_f32_16x16x32_bf16(a0, b0, acc[0][0], 0, 0, 0);
        acc[0][1] = __builtin_amdgcn_mfma_f32_16x16x32_bf16(a0, b1, acc[0][1], 0, 0, 0);
        acc[1][0] = __builtin_amdgcn_mfma_f32_16x16x32_bf16(a1, b0, acc[1][0], 0, 0, 0);
        acc[1][1] = __builtin_amdgcn_mfma_f32_16x16x32_bf16(a1, b1, acc[1][1], 0, 0, 0);
    }

    ssq0 += __shfl_xor(ssq0, 16); ssq0 += __shfl_xor(ssq0, 32);
    ssq1 += __shfl_xor(ssq1, 16); ssq1 += __shfl_xor(ssq1, 32);

    float* pd = part + ((long)split * 64 + bh) * 576;
#pragma unroll
    for (int m = 0; m < 2; m++)
#pragma unroll
        for (int n = 0; n < 2; n++)
#pragma unroll
            for (int r = 0; r < 4; r++) {
                int c = m * 16 + (lane >> 4) * 4 + r;
                int d = n * 16 + row;
                if (c < CD && d < CD) pd[c * CD + d] = acc[m][n][r];
            }
    if (lane < 16) {
        float* ps = pssq + ((long)split * 64 + bh) * 32;
        ps[lane]      = ssq0;
        ps[16 + lane] = ssq1;
    }
}

// ---------------------------------------------------------------------------
// reduce split partials, normalize, scale, softmax over d (24)
// ---------------------------------------------------------------------------
__global__ __launch_bounds__(64)
void softmax_kernel(const float* __restrict__ part, const float* __restrict__ pssq,
                    const float* __restrict__ kss, const float* __restrict__ scale,
                    float* __restrict__ prob)
{
    const int blk = blockIdx.x;            // b*192 + h*24 + c
    const int b = blk / DIM;
    const int hc = blk % DIM;
    const int h = hc / CD, c = hc % CD;
    const int bh = b * 8 + h;
    const int d = threadIdx.x;

    float qs = 0.f;
    for (int s = 0; s < NSPLIT; s++) qs += pssq[((long)s * 64 + bh) * 32 + c];

    float val = -1e30f;
    if (d < CD) {
        float raw = 0.f;
        for (int s = 0; s < NSPLIT; s++) raw += part[((long)s * 64 + bh) * 576 + c * CD + d];
        float qn = fmaxf(sqrtf(qs), 1e-12f);
        float kn = fmaxf(sqrtf(kss[b * DIM + h * CD + d]), 1e-12f);
        val = raw * scale[h] / (qn * kn);
    }
    float m = val;
    for (int o = 32; o; o >>= 1) m = fmaxf(m, __shfl_xor(m, o));
    float e = (d < CD) ? expf(val - m) : 0.f;
    float s = e;
    for (int o = 32; o; o >>= 1) s += __shfl_xor(s, o);
    if (d < CD) prob[(long)blk * CD + d] = e / s;
}

// ---------------------------------------------------------------------------
// M[b][oc][gvc] = sum_c pw[oc][h*24+c] * prob[b,h,c,d]   (gvc=h*24+d), bf16
// ---------------------------------------------------------------------------
__global__ __launch_bounds__(256)
void buildm(const float* __restrict__ pw, const float* __restrict__ prob,
            short* __restrict__ M)
{
    long flat = (long)blockIdx.x * 256 + threadIdx.x;
    if (flat >= (long)NB * DIM * DIM) return;
    int bb  = (int)(flat / (DIM * DIM));
    int rem = (int)(flat % (DIM * DIM));
    int oc = rem / DIM, gvc = rem % DIM;
    int h = gvc / CD, d = gvc % CD;
    float s = 0.f;
#pragma unroll
    for (int c = 0; c < CD; c++)
        s += pw[oc * DIM + h * CD + c] * prob[((long)bb * DIM + h * CD + c) * CD + d];
    M[flat] = f2bf(s);
}

// ---------------------------------------------------------------------------
extern "C" void kernel_launch(void* const* d_in, const int* in_sizes, int n_in,
                              void* d_out, int out_size, void* d_ws, size_t ws_size,
                              hipStream_t stream)
{
    const float* kv    = (const float*)d_in[0];
    const float* q     = (const float*)d_in[1];
    const float* w1    = (const float*)d_in[2];   // (384,192)
    const float* w2    = (const float*)d_in[3];   // (384,9)
    const float* pw    = (const float*)d_in[4];   // (192,192)
    const float* scale = (const float*)d_in[5];   // (8)
    float* out = (float*)d_out;

    char* ws = (char*)d_ws;
    long off = 0;
    auto alloc = [&](long bytes) { char* p = ws + off; off += (bytes + 255) & ~255L; return p; };
    short* kvf1 = (short*)alloc((long)NB * DIM2 * HW * 2);   // 96 MiB
    short* kvb  = (short*)alloc((long)NB * DIM2 * HW * 2);   // 96 MiB
    short* wb1  = (short*)alloc((long)DIM2 * DIM * 2);
    float* kss  = (float*)alloc((long)NB * DIM * 4);
    float* part = (float*)alloc((long)NSPLIT * 64 * 576 * 4);
    float* pssq = (float*)alloc((long)NSPLIT * 64 * 32 * 4);
    float* prob = (float*)alloc((long)64 * 576 * 4);
    short* M    = (short*)alloc((long)NB * DIM * DIM * 2);

    // 1) w1 -> bf16
    prep_w1<<<DIM2 * DIM / 1024, 256, 0, stream>>>(w1, wb1);

    // 2) 1x1 conv (GEMM): kvf1 = w1 @ kv, bf16 out
    gemm_k192<24, true, false, false><<<dim3(128, NB), 256, 0, stream>>>(
        wb1, kv, kvf1, (long)DIM * HW, (long)DIM2 * HW);

    // 3) depthwise 3x3 + k sumsq
    dwconv_sumsq<<<NB * DIM2, 256, 0, stream>>>(kvf1, w2, kvb, kss);

    // 4) QK^T partials + q sumsq partials (MFMA over px)
    qk_mfma<<<dim3(NSPLIT, 64), 64, 0, stream>>>(q, kvb, part, pssq);

    // 5) softmax
    softmax_kernel<<<NB * DIM, 64, 0, stream>>>(part, pssq, kss, scale, prob);

    // 6) fold proj into attention: M[b] = pw @ blockdiag(attn[b]), bf16
    buildm<<<(int)(((long)NB * DIM * DIM + 255) / 256), 256, 0, stream>>>(pw, prob, M);

    // 7) out = M[b] @ v  (PV + proj fused), f32 out
    gemm_k192<12, false, true, true><<<dim3(128, NB), 256, 0, stream>>>(
        M, kvb + (long)DIM * HW, out, (long)DIM2 * HW, (long)DIM * HW);
}

// Round 5
// 263.530 us; speedup vs baseline: 1.1202x; 1.1202x over previous
//
#include <hip/hip_runtime.h>
#include <hip/hip_bf16.h>

#define HW 16384
#define DIM 192
#define DIM2 384
#define NB 8
#define HEADS 8
#define CD 24
#define NSPLIT 64

typedef float f32x4 __attribute__((ext_vector_type(4)));
typedef short bf16x8 __attribute__((ext_vector_type(8)));

__device__ __forceinline__ short f2bf(float f) {
    __hip_bfloat16 h = __float2bfloat16(f);
    return *reinterpret_cast<short*>(&h);
}
__device__ __forceinline__ float bf2f(short s) {
    __hip_bfloat16 h = *reinterpret_cast<__hip_bfloat16*>(&s);
    return __bfloat162float(h);
}

// ---------------------------------------------------------------------------
// prep: w1 (384x192 f32) -> bf16 packed in MFMA-fragment order:
// frag (mi,c,lane) at [(mi*6+c)*64+lane]*8, elem e = w1[mi*16+(l&15)][c*32+(l>>4)*8+e]
// ---------------------------------------------------------------------------
__global__ __launch_bounds__(256)
void prep_w1(const float* __restrict__ w1, short* __restrict__ wb1)
{
    int idx = blockIdx.x * 256 + threadIdx.x;      // < 24*6*64 = 9216
    if (idx >= 9216) return;
    int mi = idx / 384, rem = idx % 384;
    int c = rem >> 6, l = rem & 63;
    int oc = mi * 16 + (l & 15);
    int kb = c * 32 + (l >> 4) * 8;
    const float* src = w1 + (long)oc * DIM + kb;
    float4 v0 = *reinterpret_cast<const float4*>(src);
    float4 v1 = *reinterpret_cast<const float4*>(src + 4);
    bf16x8 o;
    o[0]=f2bf(v0.x); o[1]=f2bf(v0.y); o[2]=f2bf(v0.z); o[3]=f2bf(v0.w);
    o[4]=f2bf(v1.x); o[5]=f2bf(v1.y); o[6]=f2bf(v1.z); o[7]=f2bf(v1.w);
    *reinterpret_cast<bf16x8*>(wb1 + (long)idx * 8) = o;
}

// ---------------------------------------------------------------------------
// MFMA GEMM, K=192: C[b][oc][px] = sum_ic A[oc][ic] * B[b][ic][px].
// Block = 128-px slab x all OC. B staged via chunked double-buffered LDS then
// all 12 B-frags hoisted to regs. A pre-packed in fragment order -> each
// A-frag load is one contiguous 1KB dwordx4. C stored via per-wave LDS
// transpose -> dwordx4/dwordx2 wide stores.
// ---------------------------------------------------------------------------
template<int NOCT, bool B_F32, bool PER_BATCH_A, bool OUT_F32>
__global__ __launch_bounds__(256, 4)
void gemm_k192(const short* __restrict__ Ab, const void* __restrict__ Bg,
               void* __restrict__ Cg, long bstrideB, long bstrideC)
{
    __shared__ short ldsch[2][128 * 40];
    __shared__ float eps[4][16 * 36];
    const int tid  = threadIdx.x;
    const int lane = tid & 63;
    const int wave = tid >> 6;
    const int px0  = blockIdx.x * 128;
    const int b    = blockIdx.y;

    const int row  = lane & 15;
    const int kgrp = lane >> 4;          // 0..3
    const short* A0 = Ab + (PER_BATCH_A ? (long)b * NOCT * 3072 : 0);

    bf16x8 aA[6], aB[6];
    auto loadA = [&](bf16x8* dst, int mi) {
#pragma unroll
        for (int c = 0; c < 6; c++)
            dst[c] = *reinterpret_cast<const bf16x8*>(
                &A0[((long)(mi * 6 + c) * 64 + lane) * 8]);
    };
    loadA(aA, 0);   // issue before staging: overlaps with B traffic

    // ---- stage one 32-k chunk of B, transposed + granule-swizzled ----
    const int q  = tid & 31;             // px quad 0..31
    const int kq = tid >> 5;             // 0..7 (4 k each)
    auto stage = [&](int c, int buf) {
        const int kk = c * 32 + kq * 4;
        short4 t0, t1, t2, t3;
        if constexpr (B_F32) {
            const float* src = (const float*)Bg + (long)b * bstrideB + (long)kk * HW + px0 + q * 4;
            float4 v0 = *(const float4*)(src);
            float4 v1 = *(const float4*)(src + HW);
            float4 v2 = *(const float4*)(src + 2L * HW);
            float4 v3 = *(const float4*)(src + 3L * HW);
            t0 = make_short4(f2bf(v0.x), f2bf(v1.x), f2bf(v2.x), f2bf(v3.x));
            t1 = make_short4(f2bf(v0.y), f2bf(v1.y), f2bf(v2.y), f2bf(v3.y));
            t2 = make_short4(f2bf(v0.z), f2bf(v1.z), f2bf(v2.z), f2bf(v3.z));
            t3 = make_short4(f2bf(v0.w), f2bf(v1.w), f2bf(v2.w), f2bf(v3.w));
        } else {
            const short* src = (const short*)Bg + (long)b * bstrideB + (long)kk * HW + px0 + q * 4;
            short4 v0 = *(const short4*)(src);
            short4 v1 = *(const short4*)(src + HW);
            short4 v2 = *(const short4*)(src + 2L * HW);
            short4 v3 = *(const short4*)(src + 3L * HW);
            t0 = make_short4(v0.x, v1.x, v2.x, v3.x);
            t1 = make_short4(v0.y, v1.y, v2.y, v3.y);
            t2 = make_short4(v0.z, v1.z, v2.z, v3.z);
            t3 = make_short4(v0.w, v1.w, v2.w, v3.w);
        }
        const int goff = (((kq >> 1) ^ (q & 3)) << 3) + (kq & 1) * 4;
        short* dst = &ldsch[buf][0];
        *(short4*)&dst[(q * 4 + 0) * 40 + goff] = t0;
        *(short4*)&dst[(q * 4 + 1) * 40 + goff] = t1;
        *(short4*)&dst[(q * 4 + 2) * 40 + goff] = t2;
        *(short4*)&dst[(q * 4 + 3) * 40 + goff] = t3;
    };

    // ---- hoist all 12 B-fragments to registers (chunk double-buffer) ----
    bf16x8 bv[2][6];
    const int bro = wave * 32 + row;
    const int sgr = (row >> 2) & 3;
    stage(0, 0);
#pragma unroll
    for (int c = 0; c < 6; c++) {
        __syncthreads();
        if (c < 5) stage(c + 1, (c + 1) & 1);
        const short* base = &ldsch[c & 1][0];
        bv[0][c] = *(const bf16x8*)&base[bro * 40 + ((kgrp ^ sgr) << 3)];
        bv[1][c] = *(const bf16x8*)&base[(bro + 16) * 40 + ((kgrp ^ sgr) << 3)];
    }

    // ---- main loop: A-prefetch ping-pong + MFMA; LDS-transpose epilogue ----
    const int ocl = lane >> 2;           // 0..15 (epilogue row)
    auto computeStore = [&](const bf16x8* a, int mi) {
        f32x4 acc0 = (f32x4){0.f, 0.f, 0.f, 0.f};
        f32x4 acc1 = (f32x4){0.f, 0.f, 0.f, 0.f};
#pragma unroll
        for (int c = 0; c < 6; c++) {
            acc0 = __builtin_amdgcn_mfma_f32_16x16x32_bf16(a[c], bv[0][c], acc0, 0, 0, 0);
            acc1 = __builtin_amdgcn_mfma_f32_16x16x32_bf16(a[c], bv[1][c], acc1, 0, 0, 0);
        }
        float* ep = &eps[wave][0];
#pragma unroll
        for (int r = 0; r < 4; r++) {
            ep[(kgrp * 4 + r) * 36 + row]      = acc0[r];
            ep[(kgrp * 4 + r) * 36 + 16 + row] = acc1[r];
        }
        // wave-internal LDS ordering (lgkmcnt) — no barrier needed
#pragma unroll
        for (int t = 0; t < 2; t++) {
            const int pxq = (lane & 3) + t * 4;          // 0..7
            f32x4 vv = *reinterpret_cast<const f32x4*>(&ep[ocl * 36 + pxq * 4]);
            long off = (long)b * bstrideC + (long)(mi * 16 + ocl) * HW
                     + px0 + wave * 32 + pxq * 4;
            if constexpr (OUT_F32) {
                *reinterpret_cast<f32x4*>((float*)Cg + off) = vv;
            } else {
                *reinterpret_cast<short4*>((short*)Cg + off) =
                    make_short4(f2bf(vv[0]), f2bf(vv[1]), f2bf(vv[2]), f2bf(vv[3]));
            }
        }
    };

    for (int mi = 0; mi < NOCT; mi += 2) {
        loadA(aB, mi + 1);
        computeStore(aA, mi);
        if (mi + 2 < NOCT) loadA(aA, mi + 2);
        computeStore(aB, mi + 1);
    }
}

// ---------------------------------------------------------------------------
// depthwise 3x3 (pad 1), one 128x128 image per block; bf16 in/out,
// fused sum-of-squares for k channels (gc < 192).
// ---------------------------------------------------------------------------
__global__ __launch_bounds__(256)
void dwconv_sumsq(const short* __restrict__ in, const float* __restrict__ w2,
                  short* __restrict__ outp, float* __restrict__ kss)
{
    __shared__ short img[16384];
    __shared__ float red[4];
    const long bgc = blockIdx.x;           // b*384 + gc
    const int  gc  = (int)(bgc % DIM2);
    const int  b   = (int)(bgc / DIM2);
    const int  tid = threadIdx.x;
    const short* src = in + (bgc << 14);
#pragma unroll
    for (int j = 0; j < 16; j++) {
        int idx = (tid + j * 256) * 4;
        *reinterpret_cast<short4*>(&img[idx]) = *reinterpret_cast<const short4*>(&src[idx]);
    }
    float wv[9];
#pragma unroll
    for (int i = 0; i < 9; i++) wv[i] = w2[gc * 9 + i];
    __syncthreads();

    short* dst = outp + (bgc << 14);
    float ssq = 0.f;
    for (int j = 0; j < 64; j++) {
        int px = tid + j * 256;
        int y = px >> 7, x = px & 127;
        float s = 0.f;
#pragma unroll
        for (int dy = 0; dy < 3; dy++) {
            int yy = y + dy - 1;
            if ((unsigned)yy > 127u) continue;
#pragma unroll
            for (int dx = 0; dx < 3; dx++) {
                int xx = x + dx - 1;
                if ((unsigned)xx > 127u) continue;
                s += wv[dy * 3 + dx] * bf2f(img[yy * 128 + xx]);
            }
        }
        dst[px] = f2bf(s);
        ssq += s * s;
    }
    for (int o = 32; o; o >>= 1) ssq += __shfl_xor(ssq, o);
    if ((tid & 63) == 0) red[tid >> 6] = ssq;
    __syncthreads();
    if (gc < DIM && tid == 0)
        kss[b * DIM + gc] = red[0] + red[1] + red[2] + red[3];
}

// ---------------------------------------------------------------------------
// QK^T via MFMA over contiguous px. Zero LDS/transpose. Grid (NSPLIT, 64 bh);
// 1 wave computes 32x32 over HW/NSPLIT px. Fused q sumsq partials.
// ---------------------------------------------------------------------------
__global__ __launch_bounds__(64)
void qk_mfma(const float* __restrict__ q, const short* __restrict__ kvb,
             float* __restrict__ part, float* __restrict__ pssq)
{
    const int split = blockIdx.x;          // 0..NSPLIT-1
    const int bh    = blockIdx.y;          // b*8 + h
    const int b = bh >> 3, h = bh & 7;
    const int lane = threadIdx.x;
    const int row = lane & 15;
    const int kg  = (lane >> 4) * 8;
    const int CHUNK = HW / NSPLIT;         // 256

    const int qr1 = min(h * CD + 16 + row, DIM - 1);   // clamp (h=7 tail OOB)
    const float* q0 = q + ((long)b * DIM + h * CD + row) * HW + split * CHUNK + kg;
    const float* q1 = q + ((long)b * DIM + qr1) * HW + split * CHUNK + kg;
    const short* k0 = kvb + ((long)b * DIM2 + h * CD + row) * HW + split * CHUNK + kg;
    const short* k1 = k0 + 16L * HW;

    f32x4 acc[2][2];
#pragma unroll
    for (int m = 0; m < 2; m++)
#pragma unroll
        for (int n = 0; n < 2; n++) acc[m][n] = (f32x4){0.f, 0.f, 0.f, 0.f};
    float ssq0 = 0.f, ssq1 = 0.f;

#pragma unroll
    for (int s = 0; s < CHUNK / 32; s++) {
        const int px = s * 32;
        float4 qa = *reinterpret_cast<const float4*>(q0 + px);
        float4 qb = *reinterpret_cast<const float4*>(q0 + px + 4);
        float4 qc = *reinterpret_cast<const float4*>(q1 + px);
        float4 qd = *reinterpret_cast<const float4*>(q1 + px + 4);
        bf16x8 b0 = *reinterpret_cast<const bf16x8*>(k0 + px);
        bf16x8 b1 = *reinterpret_cast<const bf16x8*>(k1 + px);
        ssq0 += qa.x*qa.x + qa.y*qa.y + qa.z*qa.z + qa.w*qa.w
              + qb.x*qb.x + qb.y*qb.y + qb.z*qb.z + qb.w*qb.w;
        ssq1 += qc.x*qc.x + qc.y*qc.y + qc.z*qc.z + qc.w*qc.w
              + qd.x*qd.x + qd.y*qd.y + qd.z*qd.z + qd.w*qd.w;
        bf16x8 a0, a1;
        a0[0]=f2bf(qa.x); a0[1]=f2bf(qa.y); a0[2]=f2bf(qa.z); a0[3]=f2bf(qa.w);
        a0[4]=f2bf(qb.x); a0[5]=f2bf(qb.y); a0[6]=f2bf(qb.z); a0[7]=f2bf(qb.w);
        a1[0]=f2bf(qc.x); a1[1]=f2bf(qc.y); a1[2]=f2bf(qc.z); a1[3]=f2bf(qc.w);
        a1[4]=f2bf(qd.x); a1[5]=f2bf(qd.y); a1[6]=f2bf(qd.z); a1[7]=f2bf(qd.w);
        acc[0][0] = __builtin_amdgcn_mfma_f32_16x16x32_bf16(a0, b0, acc[0][0], 0, 0, 0);
        acc[0][1] = __builtin_amdgcn_mfma_f32_16x16x32_bf16(a0, b1, acc[0][1], 0, 0, 0);
        acc[1][0] = __builtin_amdgcn_mfma_f32_16x16x32_bf16(a1, b0, acc[1][0], 0, 0, 0);
        acc[1][1] = __builtin_amdgcn_mfma_f32_16x16x32_bf16(a1, b1, acc[1][1], 0, 0, 0);
    }

    ssq0 += __shfl_xor(ssq0, 16); ssq0 += __shfl_xor(ssq0, 32);
    ssq1 += __shfl_xor(ssq1, 16); ssq1 += __shfl_xor(ssq1, 32);

    float* pd = part + ((long)split * 64 + bh) * 576;
#pragma unroll
    for (int m = 0; m < 2; m++)
#pragma unroll
        for (int n = 0; n < 2; n++)
#pragma unroll
            for (int r = 0; r < 4; r++) {
                int c = m * 16 + (lane >> 4) * 4 + r;
                int d = n * 16 + row;
                if (c < CD && d < CD) pd[c * CD + d] = acc[m][n][r];
            }
    if (lane < 16) {
        float* ps = pssq + ((long)split * 64 + bh) * 32;
        ps[lane]      = ssq0;
        ps[16 + lane] = ssq1;
    }
}

// ---------------------------------------------------------------------------
// reduce split partials, normalize, scale, softmax over d (24)
// ---------------------------------------------------------------------------
__global__ __launch_bounds__(64)
void softmax_kernel(const float* __restrict__ part, const float* __restrict__ pssq,
                    const float* __restrict__ kss, const float* __restrict__ scale,
                    float* __restrict__ prob)
{
    const int blk = blockIdx.x;            // b*192 + h*24 + c
    const int b = blk / DIM;
    const int hc = blk % DIM;
    const int h = hc / CD, c = hc % CD;
    const int bh = b * 8 + h;
    const int d = threadIdx.x;

    float qs = 0.f;
    for (int s = 0; s < NSPLIT; s++) qs += pssq[((long)s * 64 + bh) * 32 + c];

    float val = -1e30f;
    if (d < CD) {
        float raw = 0.f;
        for (int s = 0; s < NSPLIT; s++) raw += part[((long)s * 64 + bh) * 576 + c * CD + d];
        float qn = fmaxf(sqrtf(qs), 1e-12f);
        float kn = fmaxf(sqrtf(kss[b * DIM + h * CD + d]), 1e-12f);
        val = raw * scale[h] / (qn * kn);
    }
    float m = val;
    for (int o = 32; o; o >>= 1) m = fmaxf(m, __shfl_xor(m, o));
    float e = (d < CD) ? expf(val - m) : 0.f;
    float s = e;
    for (int o = 32; o; o >>= 1) s += __shfl_xor(s, o);
    if (d < CD) prob[(long)blk * CD + d] = e / s;
}

// ---------------------------------------------------------------------------
// M[b] = pw @ blockdiag(attn[b]) in bf16, written directly in packed
// MFMA-fragment order: frag (b,mi,c,lane) elem e = M[mi*16+(l&15)][c*32+(l>>4)*8+e]
// ---------------------------------------------------------------------------
__global__ __launch_bounds__(256)
void buildm(const float* __restrict__ pw, const float* __restrict__ prob,
            short* __restrict__ M)
{
    int idx = blockIdx.x * 256 + threadIdx.x;      // < 8 * 12*6*64 = 36864
    if (idx >= 36864) return;
    int b   = idx / 4608, rem = idx % 4608;
    int mi  = rem / 384, r2 = rem % 384;
    int c   = r2 >> 6, l = r2 & 63;
    int oc  = mi * 16 + (l & 15);
    int gb  = c * 32 + (l >> 4) * 8;
    bf16x8 o;
#pragma unroll
    for (int e = 0; e < 8; e++) {
        int gvc = gb + e;
        int h = gvc / CD, d = gvc % CD;
        float s = 0.f;
#pragma unroll
        for (int cc = 0; cc < CD; cc++)
            s += pw[oc * DIM + h * CD + cc] * prob[((long)b * DIM + h * CD + cc) * CD + d];
        o[e] = f2bf(s);
    }
    *reinterpret_cast<bf16x8*>(M + (long)idx * 8) = o;
}

// ---------------------------------------------------------------------------
extern "C" void kernel_launch(void* const* d_in, const int* in_sizes, int n_in,
                              void* d_out, int out_size, void* d_ws, size_t ws_size,
                              hipStream_t stream)
{
    const float* kv    = (const float*)d_in[0];
    const float* q     = (const float*)d_in[1];
    const float* w1    = (const float*)d_in[2];   // (384,192)
    const float* w2    = (const float*)d_in[3];   // (384,9)
    const float* pw    = (const float*)d_in[4];   // (192,192)
    const float* scale = (const float*)d_in[5];   // (8)
    float* out = (float*)d_out;

    char* ws = (char*)d_ws;
    long off = 0;
    auto alloc = [&](long bytes) { char* p = ws + off; off += (bytes + 255) & ~255L; return p; };
    short* kvf1 = (short*)alloc((long)NB * DIM2 * HW * 2);   // 96 MiB
    short* kvb  = (short*)alloc((long)NB * DIM2 * HW * 2);   // 96 MiB
    short* wb1  = (short*)alloc((long)DIM2 * DIM * 2);
    float* kss  = (float*)alloc((long)NB * DIM * 4);
    float* part = (float*)alloc((long)NSPLIT * 64 * 576 * 4);
    float* pssq = (float*)alloc((long)NSPLIT * 64 * 32 * 4);
    float* prob = (float*)alloc((long)64 * 576 * 4);
    short* M    = (short*)alloc((long)NB * DIM * DIM * 2);

    // 1) w1 -> bf16, packed fragment order
    prep_w1<<<36, 256, 0, stream>>>(w1, wb1);

    // 2) 1x1 conv (GEMM): kvf1 = w1 @ kv, bf16 out
    gemm_k192<24, true, false, false><<<dim3(128, NB), 256, 0, stream>>>(
        wb1, kv, kvf1, (long)DIM * HW, (long)DIM2 * HW);

    // 3) depthwise 3x3 + k sumsq
    dwconv_sumsq<<<NB * DIM2, 256, 0, stream>>>(kvf1, w2, kvb, kss);

    // 4) QK^T partials + q sumsq partials (MFMA over px)
    qk_mfma<<<dim3(NSPLIT, 64), 64, 0, stream>>>(q, kvb, part, pssq);

    // 5) softmax
    softmax_kernel<<<NB * DIM, 64, 0, stream>>>(part, pssq, kss, scale, prob);

    // 6) fold proj into attention: M[b] packed in fragment order, bf16
    buildm<<<144, 256, 0, stream>>>(pw, prob, M);

    // 7) out = M[b] @ v  (PV + proj fused), f32 out
    gemm_k192<12, false, true, true><<<dim3(128, NB), 256, 0, stream>>>(
        M, kvb + (long)DIM * HW, out, (long)DIM2 * HW, (long)DIM * HW);
}

// Round 6
// 210.593 us; speedup vs baseline: 1.4018x; 1.2514x over previous
//
#include <hip/hip_runtime.h>
#include <hip/hip_bf16.h>

#define HW 16384
#define DIM 192
#define DIM2 384
#define NB 8
#define HEADS 8
#define CD 24
#define NSPLIT 64

typedef float f32x4 __attribute__((ext_vector_type(4)));
typedef short bf16x8 __attribute__((ext_vector_type(8)));

__device__ __forceinline__ short f2bf(float f) {
    __hip_bfloat16 h = __float2bfloat16(f);
    return *reinterpret_cast<short*>(&h);
}
__device__ __forceinline__ float bf2f(short s) {
    __hip_bfloat16 h = *reinterpret_cast<__hip_bfloat16*>(&s);
    return __bfloat162float(h);
}

// ---------------------------------------------------------------------------
// prep: w1 (384x192 f32) -> bf16 packed in MFMA-fragment order:
// frag (mi,c,lane) at [(mi*6+c)*64+lane]*8, elem e = w1[mi*16+(l&15)][c*32+(l>>4)*8+e]
// ---------------------------------------------------------------------------
__global__ __launch_bounds__(256)
void prep_w1(const float* __restrict__ w1, short* __restrict__ wb1)
{
    int idx = blockIdx.x * 256 + threadIdx.x;      // < 24*6*64 = 9216
    if (idx >= 9216) return;
    int mi = idx / 384, rem = idx % 384;
    int c = rem >> 6, l = rem & 63;
    int oc = mi * 16 + (l & 15);
    int kb = c * 32 + (l >> 4) * 8;
    const float* src = w1 + (long)oc * DIM + kb;
    float4 v0 = *reinterpret_cast<const float4*>(src);
    float4 v1 = *reinterpret_cast<const float4*>(src + 4);
    bf16x8 o;
    o[0]=f2bf(v0.x); o[1]=f2bf(v0.y); o[2]=f2bf(v0.z); o[3]=f2bf(v0.w);
    o[4]=f2bf(v1.x); o[5]=f2bf(v1.y); o[6]=f2bf(v1.z); o[7]=f2bf(v1.w);
    *reinterpret_cast<bf16x8*>(wb1 + (long)idx * 8) = o;
}

// ---------------------------------------------------------------------------
// MFMA GEMM, K=192: C[b][oc][px] = sum_ic A[oc][ic] * B[b][ic][px].
// Block = 128-px slab x all OC. B staged via chunked double-buffered LDS then
// all 12 B-frags hoisted to regs. A pre-packed in fragment order -> each
// A-frag load is one contiguous 1KB dwordx4. C stored via per-wave LDS
// transpose -> dwordx4/dwordx2 wide stores.
// ---------------------------------------------------------------------------
template<int NOCT, bool B_F32, bool PER_BATCH_A, bool OUT_F32>
__global__ __launch_bounds__(256, 4)
void gemm_k192(const short* __restrict__ Ab, const void* __restrict__ Bg,
               void* __restrict__ Cg, long bstrideB, long bstrideC)
{
    __shared__ short ldsch[2][128 * 40];
    __shared__ float eps[4][16 * 36];
    const int tid  = threadIdx.x;
    const int lane = tid & 63;
    const int wave = tid >> 6;
    const int px0  = blockIdx.x * 128;
    const int b    = blockIdx.y;

    const int row  = lane & 15;
    const int kgrp = lane >> 4;          // 0..3
    const short* A0 = Ab + (PER_BATCH_A ? (long)b * NOCT * 3072 : 0);

    bf16x8 aA[6], aB[6];
    auto loadA = [&](bf16x8* dst, int mi) {
#pragma unroll
        for (int c = 0; c < 6; c++)
            dst[c] = *reinterpret_cast<const bf16x8*>(
                &A0[((long)(mi * 6 + c) * 64 + lane) * 8]);
    };
    loadA(aA, 0);   // issue before staging: overlaps with B traffic

    // ---- stage one 32-k chunk of B, transposed + granule-swizzled ----
    const int q  = tid & 31;             // px quad 0..31
    const int kq = tid >> 5;             // 0..7 (4 k each)
    auto stage = [&](int c, int buf) {
        const int kk = c * 32 + kq * 4;
        short4 t0, t1, t2, t3;
        if constexpr (B_F32) {
            const float* src = (const float*)Bg + (long)b * bstrideB + (long)kk * HW + px0 + q * 4;
            float4 v0 = *(const float4*)(src);
            float4 v1 = *(const float4*)(src + HW);
            float4 v2 = *(const float4*)(src + 2L * HW);
            float4 v3 = *(const float4*)(src + 3L * HW);
            t0 = make_short4(f2bf(v0.x), f2bf(v1.x), f2bf(v2.x), f2bf(v3.x));
            t1 = make_short4(f2bf(v0.y), f2bf(v1.y), f2bf(v2.y), f2bf(v3.y));
            t2 = make_short4(f2bf(v0.z), f2bf(v1.z), f2bf(v2.z), f2bf(v3.z));
            t3 = make_short4(f2bf(v0.w), f2bf(v1.w), f2bf(v2.w), f2bf(v3.w));
        } else {
            const short* src = (const short*)Bg + (long)b * bstrideB + (long)kk * HW + px0 + q * 4;
            short4 v0 = *(const short4*)(src);
            short4 v1 = *(const short4*)(src + HW);
            short4 v2 = *(const short4*)(src + 2L * HW);
            short4 v3 = *(const short4*)(src + 3L * HW);
            t0 = make_short4(v0.x, v1.x, v2.x, v3.x);
            t1 = make_short4(v0.y, v1.y, v2.y, v3.y);
            t2 = make_short4(v0.z, v1.z, v2.z, v3.z);
            t3 = make_short4(v0.w, v1.w, v2.w, v3.w);
        }
        const int goff = (((kq >> 1) ^ (q & 3)) << 3) + (kq & 1) * 4;
        short* dst = &ldsch[buf][0];
        *(short4*)&dst[(q * 4 + 0) * 40 + goff] = t0;
        *(short4*)&dst[(q * 4 + 1) * 40 + goff] = t1;
        *(short4*)&dst[(q * 4 + 2) * 40 + goff] = t2;
        *(short4*)&dst[(q * 4 + 3) * 40 + goff] = t3;
    };

    // ---- hoist all 12 B-fragments to registers (chunk double-buffer) ----
    bf16x8 bv[2][6];
    const int bro = wave * 32 + row;
    const int sgr = (row >> 2) & 3;
    stage(0, 0);
#pragma unroll
    for (int c = 0; c < 6; c++) {
        __syncthreads();
        if (c < 5) stage(c + 1, (c + 1) & 1);
        const short* base = &ldsch[c & 1][0];
        bv[0][c] = *(const bf16x8*)&base[bro * 40 + ((kgrp ^ sgr) << 3)];
        bv[1][c] = *(const bf16x8*)&base[(bro + 16) * 40 + ((kgrp ^ sgr) << 3)];
    }

    // ---- main loop: A-prefetch ping-pong + MFMA; LDS-transpose epilogue ----
    const int ocl = lane >> 2;           // 0..15 (epilogue row)
    auto computeStore = [&](const bf16x8* a, int mi) {
        f32x4 acc0 = (f32x4){0.f, 0.f, 0.f, 0.f};
        f32x4 acc1 = (f32x4){0.f, 0.f, 0.f, 0.f};
#pragma unroll
        for (int c = 0; c < 6; c++) {
            acc0 = __builtin_amdgcn_mfma_f32_16x16x32_bf16(a[c], bv[0][c], acc0, 0, 0, 0);
            acc1 = __builtin_amdgcn_mfma_f32_16x16x32_bf16(a[c], bv[1][c], acc1, 0, 0, 0);
        }
        float* ep = &eps[wave][0];
#pragma unroll
        for (int r = 0; r < 4; r++) {
            ep[(kgrp * 4 + r) * 36 + row]      = acc0[r];
            ep[(kgrp * 4 + r) * 36 + 16 + row] = acc1[r];
        }
        // wave-internal LDS ordering (lgkmcnt) — no barrier needed
#pragma unroll
        for (int t = 0; t < 2; t++) {
            const int pxq = (lane & 3) + t * 4;          // 0..7
            f32x4 vv = *reinterpret_cast<const f32x4*>(&ep[ocl * 36 + pxq * 4]);
            long off = (long)b * bstrideC + (long)(mi * 16 + ocl) * HW
                     + px0 + wave * 32 + pxq * 4;
            if constexpr (OUT_F32) {
                *reinterpret_cast<f32x4*>((float*)Cg + off) = vv;
            } else {
                *reinterpret_cast<short4*>((short*)Cg + off) =
                    make_short4(f2bf(vv[0]), f2bf(vv[1]), f2bf(vv[2]), f2bf(vv[3]));
            }
        }
    };

    for (int mi = 0; mi < NOCT; mi += 2) {
        loadA(aB, mi + 1);
        computeStore(aA, mi);
        if (mi + 2 < NOCT) loadA(aA, mi + 2);
        computeStore(aB, mi + 1);
    }
}

// ---------------------------------------------------------------------------
// depthwise 3x3 (pad 1): register-rolling rows, NO LDS image.
// Thread (tx,ty) owns an 8x8 patch: tx = x-group (8 px), ty = y-strip.
// Per input row: one b128 global load (bf16x8) + 2 __shfl for lane halos
// (at tx==0/15 the halo is the image edge = 0, masking the cross-ty shfl).
// Fused sum-of-squares for k channels (gc < 192).
// ---------------------------------------------------------------------------
__global__ __launch_bounds__(256)
void dwconv_sumsq(const short* __restrict__ in, const float* __restrict__ w2,
                  short* __restrict__ outp, float* __restrict__ kss)
{
    __shared__ float red[4];
    const long bgc = blockIdx.x;           // b*384 + gc
    const int  gc  = (int)(bgc % DIM2);
    const int  b   = (int)(bgc / DIM2);
    const int  tid = threadIdx.x;
    const int  tx  = tid & 15;             // x-group: px [tx*8, tx*8+8)
    const int  ty  = tid >> 4;             // y-strip: rows [ty*8, ty*8+8)
    const int  lane = tid & 63;
    const int  x0 = tx * 8;
    const int  y0 = ty * 8;
    const short* src = in + (bgc << 14);
    short* dst = outp + (bgc << 14);

    float w[9];
#pragma unroll
    for (int i = 0; i < 9; i++) w[i] = w2[gc * 9 + i];   // wave-uniform -> SGPR

    // row buffer layout: r[0] = left halo (x0-1), r[1..8] = own px, r[9] = right halo
    float r0[10], r1[10], r2[10];
    auto loadRow = [&](float* r, int y) {
        if ((unsigned)y > 127u) {
#pragma unroll
            for (int i = 0; i < 10; i++) r[i] = 0.f;
            return;
        }
        bf16x8 v = *reinterpret_cast<const bf16x8*>(&src[y * 128 + x0]);
#pragma unroll
        for (int i = 0; i < 8; i++) r[i + 1] = bf2f(v[i]);
        float left  = __shfl(r[8], lane - 1);
        float right = __shfl(r[1], lane + 1);
        r[0] = (tx == 0)  ? 0.f : left;
        r[9] = (tx == 15) ? 0.f : right;
    };

    loadRow(r0, y0 - 1);
    loadRow(r1, y0);
    float ssq = 0.f;
#pragma unroll
    for (int k = 0; k < 8; k++) {
        const int yy = y0 + k;
        loadRow(r2, yy + 1);
        bf16x8 o;
#pragma unroll
        for (int j = 0; j < 8; j++) {
            float s = r0[j] * w[0] + r0[j + 1] * w[1] + r0[j + 2] * w[2]
                    + r1[j] * w[3] + r1[j + 1] * w[4] + r1[j + 2] * w[5]
                    + r2[j] * w[6] + r2[j + 1] * w[7] + r2[j + 2] * w[8];
            o[j] = f2bf(s);
            ssq += s * s;
        }
        *reinterpret_cast<bf16x8*>(&dst[yy * 128 + x0]) = o;
#pragma unroll
        for (int i = 0; i < 10; i++) { r0[i] = r1[i]; r1[i] = r2[i]; }
    }

    for (int o = 32; o; o >>= 1) ssq += __shfl_xor(ssq, o);
    if ((tid & 63) == 0) red[tid >> 6] = ssq;
    __syncthreads();
    if (gc < DIM && tid == 0)
        kss[b * DIM + gc] = red[0] + red[1] + red[2] + red[3];
}

// ---------------------------------------------------------------------------
// QK^T via MFMA over contiguous px. Zero LDS/transpose. Grid (NSPLIT, 64 bh);
// 1 wave computes 32x32 over HW/NSPLIT px. Fused q sumsq partials.
// ---------------------------------------------------------------------------
__global__ __launch_bounds__(64)
void qk_mfma(const float* __restrict__ q, const short* __restrict__ kvb,
             float* __restrict__ part, float* __restrict__ pssq)
{
    const int split = blockIdx.x;          // 0..NSPLIT-1
    const int bh    = blockIdx.y;          // b*8 + h
    const int b = bh >> 3, h = bh & 7;
    const int lane = threadIdx.x;
    const int row = lane & 15;
    const int kg  = (lane >> 4) * 8;
    const int CHUNK = HW / NSPLIT;         // 256

    const int qr1 = min(h * CD + 16 + row, DIM - 1);   // clamp (h=7 tail OOB)
    const float* q0 = q + ((long)b * DIM + h * CD + row) * HW + split * CHUNK + kg;
    const float* q1 = q + ((long)b * DIM + qr1) * HW + split * CHUNK + kg;
    const short* k0 = kvb + ((long)b * DIM2 + h * CD + row) * HW + split * CHUNK + kg;
    const short* k1 = k0 + 16L * HW;

    f32x4 acc[2][2];
#pragma unroll
    for (int m = 0; m < 2; m++)
#pragma unroll
        for (int n = 0; n < 2; n++) acc[m][n] = (f32x4){0.f, 0.f, 0.f, 0.f};
    float ssq0 = 0.f, ssq1 = 0.f;

#pragma unroll
    for (int s = 0; s < CHUNK / 32; s++) {
        const int px = s * 32;
        float4 qa = *reinterpret_cast<const float4*>(q0 + px);
        float4 qb = *reinterpret_cast<const float4*>(q0 + px + 4);
        float4 qc = *reinterpret_cast<const float4*>(q1 + px);
        float4 qd = *reinterpret_cast<const float4*>(q1 + px + 4);
        bf16x8 b0 = *reinterpret_cast<const bf16x8*>(k0 + px);
        bf16x8 b1 = *reinterpret_cast<const bf16x8*>(k1 + px);
        ssq0 += qa.x*qa.x + qa.y*qa.y + qa.z*qa.z + qa.w*qa.w
              + qb.x*qb.x + qb.y*qb.y + qb.z*qb.z + qb.w*qb.w;
        ssq1 += qc.x*qc.x + qc.y*qc.y + qc.z*qc.z + qc.w*qc.w
              + qd.x*qd.x + qd.y*qd.y + qd.z*qd.z + qd.w*qd.w;
        bf16x8 a0, a1;
        a0[0]=f2bf(qa.x); a0[1]=f2bf(qa.y); a0[2]=f2bf(qa.z); a0[3]=f2bf(qa.w);
        a0[4]=f2bf(qb.x); a0[5]=f2bf(qb.y); a0[6]=f2bf(qb.z); a0[7]=f2bf(qb.w);
        a1[0]=f2bf(qc.x); a1[1]=f2bf(qc.y); a1[2]=f2bf(qc.z); a1[3]=f2bf(qc.w);
        a1[4]=f2bf(qd.x); a1[5]=f2bf(qd.y); a1[6]=f2bf(qd.z); a1[7]=f2bf(qd.w);
        acc[0][0] = __builtin_amdgcn_mfma_f32_16x16x32_bf16(a0, b0, acc[0][0], 0, 0, 0);
        acc[0][1] = __builtin_amdgcn_mfma_f32_16x16x32_bf16(a0, b1, acc[0][1], 0, 0, 0);
        acc[1][0] = __builtin_amdgcn_mfma_f32_16x16x32_bf16(a1, b0, acc[1][0], 0, 0, 0);
        acc[1][1] = __builtin_amdgcn_mfma_f32_16x16x32_bf16(a1, b1, acc[1][1], 0, 0, 0);
    }

    ssq0 += __shfl_xor(ssq0, 16); ssq0 += __shfl_xor(ssq0, 32);
    ssq1 += __shfl_xor(ssq1, 16); ssq1 += __shfl_xor(ssq1, 32);

    float* pd = part + ((long)split * 64 + bh) * 576;
#pragma unroll
    for (int m = 0; m < 2; m++)
#pragma unroll
        for (int n = 0; n < 2; n++)
#pragma unroll
            for (int r = 0; r < 4; r++) {
                int c = m * 16 + (lane >> 4) * 4 + r;
                int d = n * 16 + row;
                if (c < CD && d < CD) pd[c * CD + d] = acc[m][n][r];
            }
    if (lane < 16) {
        float* ps = pssq + ((long)split * 64 + bh) * 32;
        ps[lane]      = ssq0;
        ps[16 + lane] = ssq1;
    }
}

// ---------------------------------------------------------------------------
// reduce split partials, normalize, scale, softmax over d (24)
// ---------------------------------------------------------------------------
__global__ __launch_bounds__(64)
void softmax_kernel(const float* __restrict__ part, const float* __restrict__ pssq,
                    const float* __restrict__ kss, const float* __restrict__ scale,
                    float* __restrict__ prob)
{
    const int blk = blockIdx.x;            // b*192 + h*24 + c
    const int b = blk / DIM;
    const int hc = blk % DIM;
    const int h = hc / CD, c = hc % CD;
    const int bh = b * 8 + h;
    const int d = threadIdx.x;

    float qs = 0.f;
    for (int s = 0; s < NSPLIT; s++) qs += pssq[((long)s * 64 + bh) * 32 + c];

    float val = -1e30f;
    if (d < CD) {
        float raw = 0.f;
        for (int s = 0; s < NSPLIT; s++) raw += part[((long)s * 64 + bh) * 576 + c * CD + d];
        float qn = fmaxf(sqrtf(qs), 1e-12f);
        float kn = fmaxf(sqrtf(kss[b * DIM + h * CD + d]), 1e-12f);
        val = raw * scale[h] / (qn * kn);
    }
    float m = val;
    for (int o = 32; o; o >>= 1) m = fmaxf(m, __shfl_xor(m, o));
    float e = (d < CD) ? expf(val - m) : 0.f;
    float s = e;
    for (int o = 32; o; o >>= 1) s += __shfl_xor(s, o);
    if (d < CD) prob[(long)blk * CD + d] = e / s;
}

// ---------------------------------------------------------------------------
// M[b] = pw @ blockdiag(attn[b]) in bf16, written directly in packed
// MFMA-fragment order: frag (b,mi,c,lane) elem e = M[mi*16+(l&15)][c*32+(l>>4)*8+e]
// ---------------------------------------------------------------------------
__global__ __launch_bounds__(256)
void buildm(const float* __restrict__ pw, const float* __restrict__ prob,
            short* __restrict__ M)
{
    int idx = blockIdx.x * 256 + threadIdx.x;      // < 8 * 12*6*64 = 36864
    if (idx >= 36864) return;
    int b   = idx / 4608, rem = idx % 4608;
    int mi  = rem / 384, r2 = rem % 384;
    int c   = r2 >> 6, l = r2 & 63;
    int oc  = mi * 16 + (l & 15);
    int gb  = c * 32 + (l >> 4) * 8;
    bf16x8 o;
#pragma unroll
    for (int e = 0; e < 8; e++) {
        int gvc = gb + e;
        int h = gvc / CD, d = gvc % CD;
        float s = 0.f;
#pragma unroll
        for (int cc = 0; cc < CD; cc++)
            s += pw[oc * DIM + h * CD + cc] * prob[((long)b * DIM + h * CD + cc) * CD + d];
        o[e] = f2bf(s);
    }
    *reinterpret_cast<bf16x8*>(M + (long)idx * 8) = o;
}

// ---------------------------------------------------------------------------
extern "C" void kernel_launch(void* const* d_in, const int* in_sizes, int n_in,
                              void* d_out, int out_size, void* d_ws, size_t ws_size,
                              hipStream_t stream)
{
    const float* kv    = (const float*)d_in[0];
    const float* q     = (const float*)d_in[1];
    const float* w1    = (const float*)d_in[2];   // (384,192)
    const float* w2    = (const float*)d_in[3];   // (384,9)
    const float* pw    = (const float*)d_in[4];   // (192,192)
    const float* scale = (const float*)d_in[5];   // (8)
    float* out = (float*)d_out;

    char* ws = (char*)d_ws;
    long off = 0;
    auto alloc = [&](long bytes) { char* p = ws + off; off += (bytes + 255) & ~255L; return p; };
    short* kvf1 = (short*)alloc((long)NB * DIM2 * HW * 2);   // 96 MiB
    short* kvb  = (short*)alloc((long)NB * DIM2 * HW * 2);   // 96 MiB
    short* wb1  = (short*)alloc((long)DIM2 * DIM * 2);
    float* kss  = (float*)alloc((long)NB * DIM * 4);
    float* part = (float*)alloc((long)NSPLIT * 64 * 576 * 4);
    float* pssq = (float*)alloc((long)NSPLIT * 64 * 32 * 4);
    float* prob = (float*)alloc((long)64 * 576 * 4);
    short* M    = (short*)alloc((long)NB * DIM * DIM * 2);

    // 1) w1 -> bf16, packed fragment order
    prep_w1<<<36, 256, 0, stream>>>(w1, wb1);

    // 2) 1x1 conv (GEMM): kvf1 = w1 @ kv, bf16 out
    gemm_k192<24, true, false, false><<<dim3(128, NB), 256, 0, stream>>>(
        wb1, kv, kvf1, (long)DIM * HW, (long)DIM2 * HW);

    // 3) depthwise 3x3 + k sumsq (register-rolling, no LDS)
    dwconv_sumsq<<<NB * DIM2, 256, 0, stream>>>(kvf1, w2, kvb, kss);

    // 4) QK^T partials + q sumsq partials (MFMA over px)
    qk_mfma<<<dim3(NSPLIT, 64), 64, 0, stream>>>(q, kvb, part, pssq);

    // 5) softmax
    softmax_kernel<<<NB * DIM, 64, 0, stream>>>(part, pssq, kss, scale, prob);

    // 6) fold proj into attention: M[b] packed in fragment order, bf16
    buildm<<<144, 256, 0, stream>>>(pw, prob, M);

    // 7) out = M[b] @ v  (PV + proj fused), f32 out
    gemm_k192<12, false, true, true><<<dim3(128, NB), 256, 0, stream>>>(
        M, kvb + (long)DIM * HW, out, (long)DIM2 * HW, (long)DIM * HW);
}

// Round 7
// 199.439 us; speedup vs baseline: 1.4802x; 1.0559x over previous
//
#include <hip/hip_runtime.h>
#include <hip/hip_bf16.h>

#define HW 16384
#define DIM 192
#define DIM2 384
#define NB 8
#define HEADS 8
#define CD 24
#define NSPLIT 64

typedef float f32x4 __attribute__((ext_vector_type(4)));
typedef short bf16x8 __attribute__((ext_vector_type(8)));

__device__ __forceinline__ short f2bf(float f) {
    __hip_bfloat16 h = __float2bfloat16(f);
    return *reinterpret_cast<short*>(&h);
}
__device__ __forceinline__ float bf2f(short s) {
    __hip_bfloat16 h = *reinterpret_cast<__hip_bfloat16*>(&s);
    return __bfloat162float(h);
}

// ---------------------------------------------------------------------------
// prep: w1 (384x192 f32) -> bf16 packed in MFMA-fragment order:
// frag (mi,c,lane) at [(mi*6+c)*64+lane]*8, elem e = w1[mi*16+(l&15)][c*32+(l>>4)*8+e]
// ---------------------------------------------------------------------------
__global__ __launch_bounds__(256)
void prep_w1(const float* __restrict__ w1, short* __restrict__ wb1)
{
    int idx = blockIdx.x * 256 + threadIdx.x;      // < 24*6*64 = 9216
    if (idx >= 9216) return;
    int mi = idx / 384, rem = idx % 384;
    int c = rem >> 6, l = rem & 63;
    int oc = mi * 16 + (l & 15);
    int kb = c * 32 + (l >> 4) * 8;
    const float* src = w1 + (long)oc * DIM + kb;
    float4 v0 = *reinterpret_cast<const float4*>(src);
    float4 v1 = *reinterpret_cast<const float4*>(src + 4);
    bf16x8 o;
    o[0]=f2bf(v0.x); o[1]=f2bf(v0.y); o[2]=f2bf(v0.z); o[3]=f2bf(v0.w);
    o[4]=f2bf(v1.x); o[5]=f2bf(v1.y); o[6]=f2bf(v1.z); o[7]=f2bf(v1.w);
    *reinterpret_cast<bf16x8*>(wb1 + (long)idx * 8) = o;
}

// ---------------------------------------------------------------------------
// MFMA GEMM, K=192: C[b][oc][px] = sum_ic A[oc][ic] * B[b][ic][px].
// Block = 128-px slab x all OC.
// SINGLE-SHOT staging: every thread issues all 24 B-slab vector loads
// up-front (max memory-level parallelism, one HBM latency chain), then
// cvt+transpose+LDS-write in load order (compiler inserts counted vmcnt),
// ONE barrier, hoist all 12 B-frags to registers, second barrier (B-LDS
// dies; epilogue buffer aliases it). Main loop: packed-A ping-pong + MFMA +
// LDS-transpose epilogue with wide stores. LDS = 51.2 KB -> 3 blocks/CU.
// ---------------------------------------------------------------------------
template<int NOCT, bool B_F32, bool PER_BATCH_A, bool OUT_F32>
__global__ __launch_bounds__(256, 3)
void gemm_k192(const short* __restrict__ Ab, const void* __restrict__ Bg,
               void* __restrict__ Cg, long bstrideB, long bstrideC)
{
    __shared__ short lds[128 * 200];     // B slab; aliased by epilogue later
    const int tid  = threadIdx.x;
    const int lane = tid & 63;
    const int wave = tid >> 6;
    const int px0  = blockIdx.x * 128;
    const int b    = blockIdx.y;

    const int row  = lane & 15;
    const int kgrp = lane >> 4;          // 0..3
    const short* A0 = Ab + (PER_BATCH_A ? (long)b * NOCT * 3072 : 0);

    bf16x8 aA[6], aB[6];
    auto loadA = [&](bf16x8* dst, int mi) {
#pragma unroll
        for (int c = 0; c < 6; c++)
            dst[c] = *reinterpret_cast<const bf16x8*>(
                &A0[((long)(mi * 6 + c) * 64 + lane) * 8]);
    };
    loadA(aA, 0);   // in flight alongside B staging

    // ---- single-shot stage: thread (q = px-quad, kl = k-lane) ----
    const int q  = tid & 31;             // px quad: px = 4q .. 4q+3
    const int kl = tid >> 5;             // 0..7: k = 32j + 4kl + e
    {
        float4 stf[6][4];
        short4 sth[6][4];
        if constexpr (B_F32) {
            const float* src = (const float*)Bg + (long)b * bstrideB + px0 + q * 4;
#pragma unroll
            for (int j = 0; j < 6; j++)
#pragma unroll
                for (int e = 0; e < 4; e++)
                    stf[j][e] = *(const float4*)(src + (long)(32 * j + 4 * kl + e) * HW);
        } else {
            const short* src = (const short*)Bg + (long)b * bstrideB + px0 + q * 4;
#pragma unroll
            for (int j = 0; j < 6; j++)
#pragma unroll
                for (int e = 0; e < 4; e++)
                    sth[j][e] = *(const short4*)(src + (long)(32 * j + 4 * kl + e) * HW);
        }
        const int goff = (((kl >> 1) ^ (q & 3)) << 3) + (kl & 1) * 4;
#pragma unroll
        for (int j = 0; j < 6; j++) {
            short4 t[4];
            if constexpr (B_F32) {
#pragma unroll
                for (int i = 0; i < 4; i++)
                    t[i] = make_short4(f2bf(stf[j][0][i]), f2bf(stf[j][1][i]),
                                       f2bf(stf[j][2][i]), f2bf(stf[j][3][i]));
            } else {
                t[0] = make_short4(sth[j][0].x, sth[j][1].x, sth[j][2].x, sth[j][3].x);
                t[1] = make_short4(sth[j][0].y, sth[j][1].y, sth[j][2].y, sth[j][3].y);
                t[2] = make_short4(sth[j][0].z, sth[j][1].z, sth[j][2].z, sth[j][3].z);
                t[3] = make_short4(sth[j][0].w, sth[j][1].w, sth[j][2].w, sth[j][3].w);
            }
#pragma unroll
            for (int i = 0; i < 4; i++)
                *(short4*)&lds[(q * 4 + i) * 200 + 32 * j + goff] = t[i];
        }
    }
    __syncthreads();

    // ---- hoist all 12 B-fragments to registers ----
    bf16x8 bv[2][6];
    const int bro = wave * 32 + row;
    const int sgr = (row >> 2) & 3;
#pragma unroll
    for (int c = 0; c < 6; c++) {
        bv[0][c] = *(const bf16x8*)&lds[bro * 200 + c * 32 + ((kgrp ^ sgr) << 3)];
        bv[1][c] = *(const bf16x8*)&lds[(bro + 16) * 200 + c * 32 + ((kgrp ^ sgr) << 3)];
    }
    __syncthreads();                     // B-LDS dead; epilogue aliases it

    float* ep = reinterpret_cast<float*>(&lds[0]) + wave * 576;   // 16x36 per wave

    // ---- main loop: A ping-pong + MFMA; LDS-transpose epilogue ----
    const int ocl = lane >> 2;           // 0..15 (epilogue row)
    auto computeStore = [&](const bf16x8* a, int mi) {
        f32x4 acc0 = (f32x4){0.f, 0.f, 0.f, 0.f};
        f32x4 acc1 = (f32x4){0.f, 0.f, 0.f, 0.f};
#pragma unroll
        for (int c = 0; c < 6; c++) {
            acc0 = __builtin_amdgcn_mfma_f32_16x16x32_bf16(a[c], bv[0][c], acc0, 0, 0, 0);
            acc1 = __builtin_amdgcn_mfma_f32_16x16x32_bf16(a[c], bv[1][c], acc1, 0, 0, 0);
        }
#pragma unroll
        for (int r = 0; r < 4; r++) {
            ep[(kgrp * 4 + r) * 36 + row]      = acc0[r];
            ep[(kgrp * 4 + r) * 36 + 16 + row] = acc1[r];
        }
        // wave-internal LDS ordering (lgkmcnt) — no barrier needed
#pragma unroll
        for (int t = 0; t < 2; t++) {
            const int pxq = (lane & 3) + t * 4;          // 0..7
            f32x4 vv = *reinterpret_cast<const f32x4*>(&ep[ocl * 36 + pxq * 4]);
            long off = (long)b * bstrideC + (long)(mi * 16 + ocl) * HW
                     + px0 + wave * 32 + pxq * 4;
            if constexpr (OUT_F32) {
                *reinterpret_cast<f32x4*>((float*)Cg + off) = vv;
            } else {
                *reinterpret_cast<short4*>((short*)Cg + off) =
                    make_short4(f2bf(vv[0]), f2bf(vv[1]), f2bf(vv[2]), f2bf(vv[3]));
            }
        }
    };

    for (int mi = 0; mi < NOCT; mi += 2) {
        loadA(aB, mi + 1);
        computeStore(aA, mi);
        if (mi + 2 < NOCT) loadA(aA, mi + 2);
        computeStore(aB, mi + 1);
    }
}

// ---------------------------------------------------------------------------
// depthwise 3x3 (pad 1): register-rolling rows, NO LDS image.
// Thread (tx,ty) owns an 8x8 patch; halos via __shfl. Fused k sum-of-squares.
// ---------------------------------------------------------------------------
__global__ __launch_bounds__(256)
void dwconv_sumsq(const short* __restrict__ in, const float* __restrict__ w2,
                  short* __restrict__ outp, float* __restrict__ kss)
{
    __shared__ float red[4];
    const long bgc = blockIdx.x;           // b*384 + gc
    const int  gc  = (int)(bgc % DIM2);
    const int  b   = (int)(bgc / DIM2);
    const int  tid = threadIdx.x;
    const int  tx  = tid & 15;             // x-group: px [tx*8, tx*8+8)
    const int  ty  = tid >> 4;             // y-strip: rows [ty*8, ty*8+8)
    const int  lane = tid & 63;
    const int  x0 = tx * 8;
    const int  y0 = ty * 8;
    const short* src = in + (bgc << 14);
    short* dst = outp + (bgc << 14);

    float w[9];
#pragma unroll
    for (int i = 0; i < 9; i++) w[i] = w2[gc * 9 + i];   // wave-uniform -> SGPR

    float r0[10], r1[10], r2[10];
    auto loadRow = [&](float* r, int y) {
        if ((unsigned)y > 127u) {
#pragma unroll
            for (int i = 0; i < 10; i++) r[i] = 0.f;
            return;
        }
        bf16x8 v = *reinterpret_cast<const bf16x8*>(&src[y * 128 + x0]);
#pragma unroll
        for (int i = 0; i < 8; i++) r[i + 1] = bf2f(v[i]);
        float left  = __shfl(r[8], lane - 1);
        float right = __shfl(r[1], lane + 1);
        r[0] = (tx == 0)  ? 0.f : left;
        r[9] = (tx == 15) ? 0.f : right;
    };

    loadRow(r0, y0 - 1);
    loadRow(r1, y0);
    float ssq = 0.f;
#pragma unroll
    for (int k = 0; k < 8; k++) {
        const int yy = y0 + k;
        loadRow(r2, yy + 1);
        bf16x8 o;
#pragma unroll
        for (int j = 0; j < 8; j++) {
            float s = r0[j] * w[0] + r0[j + 1] * w[1] + r0[j + 2] * w[2]
                    + r1[j] * w[3] + r1[j + 1] * w[4] + r1[j + 2] * w[5]
                    + r2[j] * w[6] + r2[j + 1] * w[7] + r2[j + 2] * w[8];
            o[j] = f2bf(s);
            ssq += s * s;
        }
        *reinterpret_cast<bf16x8*>(&dst[yy * 128 + x0]) = o;
#pragma unroll
        for (int i = 0; i < 10; i++) { r0[i] = r1[i]; r1[i] = r2[i]; }
    }

    for (int o = 32; o; o >>= 1) ssq += __shfl_xor(ssq, o);
    if ((tid & 63) == 0) red[tid >> 6] = ssq;
    __syncthreads();
    if (gc < DIM && tid == 0)
        kss[b * DIM + gc] = red[0] + red[1] + red[2] + red[3];
}

// ---------------------------------------------------------------------------
// QK^T via MFMA over contiguous px. Zero LDS/transpose. Grid (NSPLIT, 64 bh);
// 1 wave computes 32x32 over HW/NSPLIT px. Fused q sumsq partials.
// ---------------------------------------------------------------------------
__global__ __launch_bounds__(64)
void qk_mfma(const float* __restrict__ q, const short* __restrict__ kvb,
             float* __restrict__ part, float* __restrict__ pssq)
{
    const int split = blockIdx.x;          // 0..NSPLIT-1
    const int bh    = blockIdx.y;          // b*8 + h
    const int b = bh >> 3, h = bh & 7;
    const int lane = threadIdx.x;
    const int row = lane & 15;
    const int kg  = (lane >> 4) * 8;
    const int CHUNK = HW / NSPLIT;         // 256

    const int qr1 = min(h * CD + 16 + row, DIM - 1);   // clamp (h=7 tail OOB)
    const float* q0 = q + ((long)b * DIM + h * CD + row) * HW + split * CHUNK + kg;
    const float* q1 = q + ((long)b * DIM + qr1) * HW + split * CHUNK + kg;
    const short* k0 = kvb + ((long)b * DIM2 + h * CD + row) * HW + split * CHUNK + kg;
    const short* k1 = k0 + 16L * HW;

    f32x4 acc[2][2];
#pragma unroll
    for (int m = 0; m < 2; m++)
#pragma unroll
        for (int n = 0; n < 2; n++) acc[m][n] = (f32x4){0.f, 0.f, 0.f, 0.f};
    float ssq0 = 0.f, ssq1 = 0.f;

#pragma unroll
    for (int s = 0; s < CHUNK / 32; s++) {
        const int px = s * 32;
        float4 qa = *reinterpret_cast<const float4*>(q0 + px);
        float4 qb = *reinterpret_cast<const float4*>(q0 + px + 4);
        float4 qc = *reinterpret_cast<const float4*>(q1 + px);
        float4 qd = *reinterpret_cast<const float4*>(q1 + px + 4);
        bf16x8 b0 = *reinterpret_cast<const bf16x8*>(k0 + px);
        bf16x8 b1 = *reinterpret_cast<const bf16x8*>(k1 + px);
        ssq0 += qa.x*qa.x + qa.y*qa.y + qa.z*qa.z + qa.w*qa.w
              + qb.x*qb.x + qb.y*qb.y + qb.z*qb.z + qb.w*qb.w;
        ssq1 += qc.x*qc.x + qc.y*qc.y + qc.z*qc.z + qc.w*qc.w
              + qd.x*qd.x + qd.y*qd.y + qd.z*qd.z + qd.w*qd.w;
        bf16x8 a0, a1;
        a0[0]=f2bf(qa.x); a0[1]=f2bf(qa.y); a0[2]=f2bf(qa.z); a0[3]=f2bf(qa.w);
        a0[4]=f2bf(qb.x); a0[5]=f2bf(qb.y); a0[6]=f2bf(qb.z); a0[7]=f2bf(qb.w);
        a1[0]=f2bf(qc.x); a1[1]=f2bf(qc.y); a1[2]=f2bf(qc.z); a1[3]=f2bf(qc.w);
        a1[4]=f2bf(qd.x); a1[5]=f2bf(qd.y); a1[6]=f2bf(qd.z); a1[7]=f2bf(qd.w);
        acc[0][0] = __builtin_amdgcn_mfma_f32_16x16x32_bf16(a0, b0, acc[0][0], 0, 0, 0);
        acc[0][1] = __builtin_amdgcn_mfma_f32_16x16x32_bf16(a0, b1, acc[0][1], 0, 0, 0);
        acc[1][0] = __builtin_amdgcn_mfma_f32_16x16x32_bf16(a1, b0, acc[1][0], 0, 0, 0);
        acc[1][1] = __builtin_amdgcn_mfma_f32_16x16x32_bf16(a1, b1, acc[1][1], 0, 0, 0);
    }

    ssq0 += __shfl_xor(ssq0, 16); ssq0 += __shfl_xor(ssq0, 32);
    ssq1 += __shfl_xor(ssq1, 16); ssq1 += __shfl_xor(ssq1, 32);

    float* pd = part + ((long)split * 64 + bh) * 576;
#pragma unroll
    for (int m = 0; m < 2; m++)
#pragma unroll
        for (int n = 0; n < 2; n++)
#pragma unroll
            for (int r = 0; r < 4; r++) {
                int c = m * 16 + (lane >> 4) * 4 + r;
                int d = n * 16 + row;
                if (c < CD && d < CD) pd[c * CD + d] = acc[m][n][r];
            }
    if (lane < 16) {
        float* ps = pssq + ((long)split * 64 + bh) * 32;
        ps[lane]      = ssq0;
        ps[16 + lane] = ssq1;
    }
}

// ---------------------------------------------------------------------------
// reduce split partials, normalize, scale, softmax over d (24)
// ---------------------------------------------------------------------------
__global__ __launch_bounds__(64)
void softmax_kernel(const float* __restrict__ part, const float* __restrict__ pssq,
                    const float* __restrict__ kss, const float* __restrict__ scale,
                    float* __restrict__ prob)
{
    const int blk = blockIdx.x;            // b*192 + h*24 + c
    const int b = blk / DIM;
    const int hc = blk % DIM;
    const int h = hc / CD, c = hc % CD;
    const int bh = b * 8 + h;
    const int d = threadIdx.x;

    float qs = 0.f;
    for (int s = 0; s < NSPLIT; s++) qs += pssq[((long)s * 64 + bh) * 32 + c];

    float val = -1e30f;
    if (d < CD) {
        float raw = 0.f;
        for (int s = 0; s < NSPLIT; s++) raw += part[((long)s * 64 + bh) * 576 + c * CD + d];
        float qn = fmaxf(sqrtf(qs), 1e-12f);
        float kn = fmaxf(sqrtf(kss[b * DIM + h * CD + d]), 1e-12f);
        val = raw * scale[h] / (qn * kn);
    }
    float m = val;
    for (int o = 32; o; o >>= 1) m = fmaxf(m, __shfl_xor(m, o));
    float e = (d < CD) ? expf(val - m) : 0.f;
    float s = e;
    for (int o = 32; o; o >>= 1) s += __shfl_xor(s, o);
    if (d < CD) prob[(long)blk * CD + d] = e / s;
}

// ---------------------------------------------------------------------------
// M[b] = pw @ blockdiag(attn[b]) in bf16, written directly in packed
// MFMA-fragment order: frag (b,mi,c,lane) elem e = M[mi*16+(l&15)][c*32+(l>>4)*8+e]
// ---------------------------------------------------------------------------
__global__ __launch_bounds__(256)
void buildm(const float* __restrict__ pw, const float* __restrict__ prob,
            short* __restrict__ M)
{
    int idx = blockIdx.x * 256 + threadIdx.x;      // < 8 * 12*6*64 = 36864
    if (idx >= 36864) return;
    int b   = idx / 4608, rem = idx % 4608;
    int mi  = rem / 384, r2 = rem % 384;
    int c   = r2 >> 6, l = r2 & 63;
    int oc  = mi * 16 + (l & 15);
    int gb  = c * 32 + (l >> 4) * 8;
    bf16x8 o;
#pragma unroll
    for (int e = 0; e < 8; e++) {
        int gvc = gb + e;
        int h = gvc / CD, d = gvc % CD;
        float s = 0.f;
#pragma unroll
        for (int cc = 0; cc < CD; cc++)
            s += pw[oc * DIM + h * CD + cc] * prob[((long)b * DIM + h * CD + cc) * CD + d];
        o[e] = f2bf(s);
    }
    *reinterpret_cast<bf16x8*>(M + (long)idx * 8) = o;
}

// ---------------------------------------------------------------------------
extern "C" void kernel_launch(void* const* d_in, const int* in_sizes, int n_in,
                              void* d_out, int out_size, void* d_ws, size_t ws_size,
                              hipStream_t stream)
{
    const float* kv    = (const float*)d_in[0];
    const float* q     = (const float*)d_in[1];
    const float* w1    = (const float*)d_in[2];   // (384,192)
    const float* w2    = (const float*)d_in[3];   // (384,9)
    const float* pw    = (const float*)d_in[4];   // (192,192)
    const float* scale = (const float*)d_in[5];   // (8)
    float* out = (float*)d_out;

    char* ws = (char*)d_ws;
    long off = 0;
    auto alloc = [&](long bytes) { char* p = ws + off; off += (bytes + 255) & ~255L; return p; };
    short* kvf1 = (short*)alloc((long)NB * DIM2 * HW * 2);   // 96 MiB
    short* kvb  = (short*)alloc((long)NB * DIM2 * HW * 2);   // 96 MiB
    short* wb1  = (short*)alloc((long)DIM2 * DIM * 2);
    float* kss  = (float*)alloc((long)NB * DIM * 4);
    float* part = (float*)alloc((long)NSPLIT * 64 * 576 * 4);
    float* pssq = (float*)alloc((long)NSPLIT * 64 * 32 * 4);
    float* prob = (float*)alloc((long)64 * 576 * 4);
    short* M    = (short*)alloc((long)NB * DIM * DIM * 2);

    // 1) w1 -> bf16, packed fragment order
    prep_w1<<<36, 256, 0, stream>>>(w1, wb1);

    // 2) 1x1 conv (GEMM): kvf1 = w1 @ kv, bf16 out
    gemm_k192<24, true, false, false><<<dim3(128, NB), 256, 0, stream>>>(
        wb1, kv, kvf1, (long)DIM * HW, (long)DIM2 * HW);

    // 3) depthwise 3x3 + k sumsq (register-rolling, no LDS)
    dwconv_sumsq<<<NB * DIM2, 256, 0, stream>>>(kvf1, w2, kvb, kss);

    // 4) QK^T partials + q sumsq partials (MFMA over px)
    qk_mfma<<<dim3(NSPLIT, 64), 64, 0, stream>>>(q, kvb, part, pssq);

    // 5) softmax
    softmax_kernel<<<NB * DIM, 64, 0, stream>>>(part, pssq, kss, scale, prob);

    // 6) fold proj into attention: M[b] packed in fragment order, bf16
    buildm<<<144, 256, 0, stream>>>(pw, prob, M);

    // 7) out = M[b] @ v  (PV + proj fused), f32 out
    gemm_k192<12, false, true, true><<<dim3(128, NB), 256, 0, stream>>>(
        M, kvb + (long)DIM * HW, out, (long)DIM2 * HW, (long)DIM * HW);
}